// Round 3
// baseline (106.097 us; speedup 1.0000x reference)
//
#include <hip/hip_runtime.h>
#include <hip/hip_bf16.h>

// ProductLayer: B=4096, F=32, D=64, U=256
// out[:,   0:256] = lz       = E[B,2048] @ W1[2048,256]
// out[:, 256:512] = lp_inner = G[B,1024] @ V [1024,256]   (G_b = E_b E_b^T gram)
// out[:, 512:768] = lp_outer = M[B,4096] @ W2[4096,256]   (M_b = fs fs^T, rank-1 ->
//                              generated on the fly in the GEMM from fs, never stored)
// A  = [E | G] bf16 [4096, 3072]; FS = bf16 [4096, 64]; Wt = bf16 [256, 7168] (N-major)
// GEMM v3: BM=128 BN=64 BK=64, 2-phase prefetch dbuf, 384 blocks (seg2 first), direct stores.

#define KA 3072
#define KW 7168

typedef __attribute__((ext_vector_type(8))) short short8v;
typedef __attribute__((ext_vector_type(4))) float f32x4;

static __device__ __forceinline__ short f2bf(float f) {
    union { float f; unsigned u; } v; v.f = f;
    unsigned r = v.u + 0x7fffu + ((v.u >> 16) & 1u);  // RNE
    return (short)(r >> 16);
}
static __device__ __forceinline__ float bf2f(short s) {
    union { unsigned u; float f; } v; v.u = ((unsigned)(unsigned short)s) << 16;
    return v.f;
}

// ---------------- prep A: one block per batch row ----------------
__global__ __launch_bounds__(256) void prep_a(const float* __restrict__ embeds,
                                              short* __restrict__ A,
                                              short* __restrict__ FS) {
    int b = blockIdx.x;
    const float* e = embeds + (size_t)b * 2048;
    short* arow = A + (size_t)b * KA;
    __shared__ float se[2048];     // fp32 row [32][64]
    __shared__ short sebf[2048];   // bf16 row [32][64]
    __shared__ float fs[64];
    int t = threadIdx.x;

    float4 v0 = ((const float4*)e)[t * 2];
    float4 v1 = ((const float4*)e)[t * 2 + 1];
    ((float4*)se)[t * 2] = v0;
    ((float4*)se)[t * 2 + 1] = v1;
    short8v sb;
    sb[0] = f2bf(v0.x); sb[1] = f2bf(v0.y); sb[2] = f2bf(v0.z); sb[3] = f2bf(v0.w);
    sb[4] = f2bf(v1.x); sb[5] = f2bf(v1.y); sb[6] = f2bf(v1.z); sb[7] = f2bf(v1.w);
    ((short8v*)sebf)[t] = sb;
    *(short8v*)&arow[t * 8] = sb;   // E segment [0, 2048)

    __syncthreads();
    if (t < 64) {
        float s = 0.f;
        #pragma unroll
        for (int f = 0; f < 32; ++f) s += se[f * 64 + t];
        fs[t] = s;
        FS[(size_t)b * 64 + t] = f2bf(s);
    }
    __syncthreads();

    // G = E E^T via MFMA: 4 waves, one 16x16 tile each, K=64 in 2 steps
    int wid = t >> 6, lane = t & 63;
    int tm = wid >> 1, tn = wid & 1;
    int lr = lane & 15, lk = (lane >> 4) * 8;
    f32x4 g = {0.f, 0.f, 0.f, 0.f};
    #pragma unroll
    for (int ks = 0; ks < 2; ++ks) {
        short8v a  = *(const short8v*)&sebf[(tm * 16 + lr) * 64 + ks * 32 + lk];
        short8v bb = *(const short8v*)&sebf[(tn * 16 + lr) * 64 + ks * 32 + lk];
        g = __builtin_amdgcn_mfma_f32_16x16x32_bf16(a, bb, g, 0, 0, 0);
    }
    #pragma unroll
    for (int r = 0; r < 4; ++r) {
        int grow = tm * 16 + (lane >> 4) * 4 + r;  // C/D: col=lane&15, row=(lane>>4)*4+r
        int gcol = tn * 16 + lr;
        arow[2048 + grow * 32 + gcol] = f2bf(g[r]);  // G segment [2048, 3072)
    }
}

// ---------------- prep W: one block per unit u ----------------
__global__ __launch_bounds__(256) void prep_w(const float* __restrict__ lw,
                                              const float* __restrict__ iw,
                                              const float* __restrict__ ow,
                                              short* __restrict__ Wt) {
    int u = blockIdx.x;
    int t = threadIdx.x;
    short* w = Wt + (size_t)u * KW;

    for (int k = t; k < 2048; k += 256) w[k] = f2bf(lw[(size_t)k * 256 + u]);

    __shared__ float wi[32];
    if (t < 32) wi[t] = iw[u * 32 + t];
    __syncthreads();
    for (int idx = t; idx < 1024; idx += 256)
        w[2048 + idx] = f2bf(wi[idx >> 5] * wi[idx & 31]);

    const float* owu = ow + (size_t)u * 4096;
    for (int i = t; i < 512; i += 256) {
        float4 a = ((const float4*)owu)[i * 2];
        float4 b = ((const float4*)owu)[i * 2 + 1];
        short8v s;
        s[0] = f2bf(a.x); s[1] = f2bf(a.y); s[2] = f2bf(a.z); s[3] = f2bf(a.w);
        s[4] = f2bf(b.x); s[5] = f2bf(b.y); s[6] = f2bf(b.z); s[7] = f2bf(b.w);
        *(short8v*)&w[3072 + i * 8] = s;
    }
}

// ---------------- GEMM: BM=128 BN=64 BK=64, 2-phase prefetch ----------------
// grid 384: ids [0,128) seg2 (K=4096, longest, dispatched first),
//           ids [128,256) seg0 (K=2048), ids [256,384) seg1 (K=1024)
__global__ __launch_bounds__(256) void gemm_seg(const short* __restrict__ A,
                                                const short* __restrict__ Wt,
                                                const short* __restrict__ FS,
                                                float* __restrict__ out) {
    __shared__ short As[2][8192];   // seg0/1: A-tile dbuf; seg2: As[0]=M-tile, As[1]=fs[128][64]
    __shared__ short Bs[2][4096];

    int id = blockIdx.x;
    int seg, mt, nt;
    if (id < 128)      { seg = 2; mt = id >> 2;         nt = id & 3; }
    else if (id < 256) { seg = 0; mt = (id - 128) >> 2; nt = (id - 128) & 3; }
    else               { seg = 1; mt = (id - 256) >> 2; nt = (id - 256) & 3; }
    const int nk    = (seg == 0) ? 32 : (seg == 1) ? 16 : 64;
    const int a_off = (seg == 1) ? 2048 : 0;
    const int b_off = (seg == 0) ? 0 : (seg == 1) ? 2048 : 3072;
    int brow = mt * 128, bcol = nt * 64;

    int t = threadIdx.x, wid = t >> 6, lane = t & 63;
    int wr = wid >> 1, wc = wid & 1;
    int lr = lane & 15, lk = (lane >> 4) * 8;

    const short* Ag = A  + (size_t)(brow + (t >> 3)) * KA + a_off + (t & 7) * 8;
    const short* Bg = Wt + (size_t)(bcol + (t >> 3)) * KW + b_off + (t & 7) * 8;

    f32x4 acc[4][2];
    #pragma unroll
    for (int m = 0; m < 4; ++m)
        #pragma unroll
        for (int n = 0; n < 2; ++n) acc[m][n] = (f32x4){0.f, 0.f, 0.f, 0.f};

    auto stageA = [&](int p, int tt) {
        #pragma unroll
        for (int i = 0; i < 4; ++i)
            __builtin_amdgcn_global_load_lds(
                (const __attribute__((address_space(1))) void*)(Ag + (size_t)i * 32 * KA + tt * 64),
                (__attribute__((address_space(3))) void*)(&As[p][i * 2048 + wid * 512]), 16, 0, 0);
    };
    auto stageB = [&](int p, int tt) {
        #pragma unroll
        for (int i = 0; i < 2; ++i)
            __builtin_amdgcn_global_load_lds(
                (const __attribute__((address_space(1))) void*)(Bg + (size_t)i * 32 * KW + tt * 64),
                (__attribute__((address_space(3))) void*)(&Bs[p][i * 2048 + wid * 512]), 16, 0, 0);
    };
    auto compute = [&](const short* a_s, const short* b_s) {
        #pragma unroll
        for (int ks = 0; ks < 2; ++ks) {
            short8v a[4], bb[2];
            #pragma unroll
            for (int m = 0; m < 4; ++m)
                a[m] = *(const short8v*)&a_s[(wr * 64 + m * 16 + lr) * 64 + ks * 32 + lk];
            #pragma unroll
            for (int n = 0; n < 2; ++n)
                bb[n] = *(const short8v*)&b_s[(wc * 32 + n * 16 + lr) * 64 + ks * 32 + lk];
            #pragma unroll
            for (int m = 0; m < 4; ++m)
                #pragma unroll
                for (int n = 0; n < 2; ++n)
                    acc[m][n] = __builtin_amdgcn_mfma_f32_16x16x32_bf16(a[m], bb[n], acc[m][n], 0, 0, 0);
        }
    };

    if (seg != 2) {
        stageA(0, 0); stageB(0, 0);
        __syncthreads();
        int cur = 0;
        for (int tt = 0; tt < nk; ++tt) {
            if (tt + 1 < nk) { stageA(cur ^ 1, tt + 1); stageB(cur ^ 1, tt + 1); }
            compute(As[cur], Bs[cur]);
            __syncthreads();   // drains prefetched vmem; next tile ready
            cur ^= 1;
        }
    } else {
        // M-tile for k-tile tt is rank-1: M[r, tt*64+j] = fs[r][tt] * fs[r][j]
        #pragma unroll
        for (int i = 0; i < 4; ++i)   // fs rows [brow, brow+128) -> As[1] (16 KB, linear)
            __builtin_amdgcn_global_load_lds(
                (const __attribute__((address_space(1))) void*)(FS + (size_t)brow * 64 + (i * 4 + wid) * 512 + lane * 8),
                (__attribute__((address_space(3))) void*)(&As[1][(i * 4 + wid) * 512]), 16, 0, 0);
        stageB(0, 0);
        __syncthreads();              // fs + B(0) landed
        auto genA = [&](int tt) {
            const short* fss = As[1];
            #pragma unroll
            for (int i = 0; i < 4; ++i) {
                int row = i * 32 + (t >> 3);
                int j0 = (t & 7) * 8;
                float si = bf2f(fss[row * 64 + tt]);
                short8v sj = *(const short8v*)&fss[row * 64 + j0];
                short8v o;
                #pragma unroll
                for (int r = 0; r < 8; ++r) o[r] = f2bf(si * bf2f(sj[r]));
                *(short8v*)&As[0][row * 64 + j0] = o;
            }
        };
        genA(0);
        __syncthreads();              // M(0) visible
        int cur = 0;
        for (int tt = 0; tt < 64; ++tt) {
            if (tt + 1 < 64) stageB(cur ^ 1, tt + 1);
            compute(As[0], Bs[cur]);
            __syncthreads();          // all waves done reading As[0]; B(t+1) landed
            if (tt + 1 < 64) genA(tt + 1);
            __syncthreads();          // gen writes visible
            cur ^= 1;
        }
    }

    int col0 = seg * 256 + bcol + wc * 32;
    int row0 = brow + wr * 64;
    #pragma unroll
    for (int m = 0; m < 4; ++m)
        #pragma unroll
        for (int n = 0; n < 2; ++n)
            #pragma unroll
            for (int r = 0; r < 4; ++r) {
                int row = row0 + m * 16 + (lane >> 4) * 4 + r;
                int col = col0 + n * 16 + lr;
                out[(size_t)row * 768 + col] = acc[m][n][r];
            }
}

extern "C" void kernel_launch(void* const* d_in, const int* in_sizes, int n_in,
                              void* d_out, int out_size, void* d_ws, size_t ws_size,
                              hipStream_t stream) {
    const float* embeds = (const float*)d_in[0];
    const float* lw = (const float*)d_in[1];
    const float* iw = (const float*)d_in[2];
    const float* ow = (const float*)d_in[3];
    float* out = (float*)d_out;

    short* A  = (short*)d_ws;                    // 4096*3072*2 = 25,165,824 B
    short* Wt = A + (size_t)4096 * KA;           // + 256*7168*2 = 3,670,016 B
    short* FS = Wt + (size_t)256 * KW;           // + 4096*64*2 =    524,288 B

    prep_a<<<dim3(4096), dim3(256), 0, stream>>>(embeds, A, FS);
    prep_w<<<dim3(256), dim3(256), 0, stream>>>(lw, iw, ow, Wt);
    gemm_seg<<<dim3(384), dim3(256), 0, stream>>>(A, Wt, FS, out);
}